// Round 17
// baseline (28.240 us; speedup 1.0000x reference)
//
#include <hip/hip_runtime.h>

#define TT 16384
#define BB 32

typedef __attribute__((ext_vector_type(8))) short bf16x8;
typedef __attribute__((ext_vector_type(4))) float f32x4;

#define S1 2.8853900817779268f   // 2*log2(e)

__device__ __forceinline__ unsigned short f2bf(float v) {
    unsigned int u = __float_as_uint(v);
    u = (u + 0x7fffu + ((u >> 16) & 1u)) >> 16;   // RNE
    return (unsigned short)u;
}
__device__ __forceinline__ unsigned int pk2(float lo, float hi) {
    return (unsigned)f2bf(lo) | ((unsigned)f2bf(hi) << 16);
}
__device__ __forceinline__ float rcore(float v) {   // r = 1/(exp2(v)+1); tanh = 1-2r
    return __builtin_amdgcn_rcpf(__builtin_amdgcn_exp2f(v) + 1.0f);
}

// ---------------- single fused kernel, PHASE-SPLIT main loop ----------------
// Phase 1: conv for all 5 G-tiles (independent -> 5-way ILP).
// Phase 2: FC1+FC2 for all 4 position tiles (independent -> 4-way ILP).
// Everything else identical to the verified 27.8us round-16 kernel.
__device__ __forceinline__ void stage_row(char* S, const float* __restrict__ x,
                                          int b, int tb, int i) {
    const int trow = tb - 3 + i;
    uint4 h0 = {0u, 0u, 0u, 0u}, h1 = {0u, 0u, 0u, 0u};
    if (trow >= 0 && trow < TT) {
        const float4* p = (const float4*)x + (size_t)(b * TT + trow) * 4;
        float4 f0 = p[0], f1 = p[1], f2 = p[2], f3 = p[3];
        h0.x = pk2(f0.x, f0.y); h0.y = pk2(f0.z, f0.w);
        h0.z = pk2(f1.x, f1.y); h0.w = pk2(f1.z, f1.w);
        h1.x = pk2(f2.x, f2.y); h1.y = pk2(f2.z, f2.w);
        h1.z = pk2(f3.x, f3.y); h1.w = pk2(f3.z, f3.w);
    }
    const int s = (i >> 2) & 1;
    *(uint4*)(S + i * 32 + s * 16) = h0;
    *(uint4*)(S + i * 32 + (s ^ 1) * 16) = h1;
}

#define MFMA16(a, bb, cc) __builtin_amdgcn_mfma_f32_16x16x32_bf16((a), (bb), (cc), 0, 0, 0)
#define GPLANE 1040   // 65 cols * 16B

__global__ __launch_bounds__(256, 2) void rvt_one(
    const float* __restrict__ x,
    const float* __restrict__ conv_w, const float* __restrict__ conv_b,
    const float* __restrict__ fc_hid_w, const float* __restrict__ fc_hid_b,
    const float* __restrict__ fc_out_w, const float* __restrict__ fc_out_b,
    float* __restrict__ out)
{
    __shared__ __align__(16) char Sbuf[4 * 2176];
    __shared__ __align__(16) char Gbuf[4 * 6240];
    __shared__ __align__(16) float CwPad[576];    // [mt*4+r][48], S1-scaled
    __shared__ __align__(16) float FhwPad[576];   // [m<6][96], S1-scaled
    __shared__ float Small[23];                   // [0..2]=S1*cb [3..8]=S1*b1 [9..20]=w2 [21..22]=b2

    const int tid = threadIdx.x, wv = tid >> 6, l = tid & 63;
    const int n = l & 15, g = l >> 4;
    const int m = n;
    const int P0 = blockIdx.x << 8;
    const int b  = P0 >> 14;
    const int tb = (P0 & (TT - 1)) + (wv << 6);

    char* S = Sbuf + wv * 2176;
    char* G = Gbuf + wv * 6240;

    // ---- stage x rows (per-wave) ----
    stage_row(S, x, b, tb, l);
    if (l < 3) stage_row(S, x, b, tb, l + 64);

    // ---- build pre-scaled weight tables (block-cooperative, coalesced) ----
    for (int i = tid; i < 576; i += 256) FhwPad[i] = S1 * fc_hid_w[i];
    for (int s = tid; s < 576; s += 256) {
        const int r = (s / 48) & 3, kcp = s % 48;
        if (!(r < 3 && kcp >= 14 && kcp <= 16)) CwPad[s] = 0.f;
    }
    if (tid < 27) {
        const int mt = tid / 9, r = (tid % 9) / 3, kc = tid % 3;
        CwPad[(mt * 4 + r) * 48 + 14 + kc] = S1 * conv_w[tid];
    } else if (tid < 30) Small[tid - 27] = S1 * conv_b[tid - 27];
    else if (tid < 36) Small[3 + tid - 30] = S1 * fc_hid_b[tid - 30];
    else if (tid < 48) Small[9 + tid - 36] = fc_out_w[tid - 36];
    else if (tid < 50) Small[21 + tid - 48] = fc_out_b[tid - 48];
    __syncthreads();

    // ---- per-lane A-fragment gather from LDS ----
    union { uint4 u; bf16x8 f; } cv;
    bf16x8 A1[6], A2[3];
    #pragma unroll
    for (int mt = 0; mt < 3; ++mt)
        #pragma unroll
        for (int kt = 0; kt < 2; ++kt) {
            const int rr = kt * 2 + (g >> 1);
            const float* p = &CwPad[(mt * 4 + rr) * 48 + ((g & 1) * 8 - m + 15)];
            cv.u.x = pk2(p[0], p[1]);
            cv.u.y = pk2(p[2], p[3]);
            cv.u.z = pk2(p[4], p[5]);
            cv.u.w = pk2(p[6], p[7]);
            A1[mt * 2 + kt] = cv.f;
        }
    {
        const unsigned umask = (m < 6) ? 0xFFFFFFFFu : 0u;
        const int mc = (m < 6) ? m : 5;
        #pragma unroll
        for (int kt2 = 0; kt2 < 3; ++kt2) {
            const int q0 = kt2 * 32 + g * 8;
            const int wr = (q0 >= 48) ? 1 : 0;
            const int col0 = q0 - 48 * wr;
            const int oc = col0 >> 4, c0 = col0 & 15;
            const float4* fp = (const float4*)&FhwPad[mc * 96 + (oc * 2 + wr) * 16 + c0];
            float4 a = fp[0], bq = fp[1];
            cv.u.x = pk2(a.x, a.y) & umask;
            cv.u.y = pk2(a.z, a.w) & umask;
            cv.u.z = pk2(bq.x, bq.y) & umask;
            cv.u.w = pk2(bq.z, bq.w) & umask;
            A2[kt2] = cv.f;
        }
    }

    const float cbs0 = Small[0], cbs1 = Small[1], cbs2 = Small[2];
    const int r0 = g * 4;
    const float b1i0 = (r0 + 0 < 6) ? Small[3 + r0 + 0] : 0.f;
    const float b1i1 = (r0 + 1 < 6) ? Small[3 + r0 + 1] : 0.f;
    const float b1i2 = (r0 + 2 < 6) ? Small[3 + r0 + 2] : 0.f;
    const float b1i3 = (r0 + 3 < 6) ? Small[3 + r0 + 3] : 0.f;
    const float w200 = Small[9],  w201 = Small[10], w202 = Small[11];
    const float w203 = Small[12], w204 = Small[13], w205 = Small[14];
    const float w210 = Small[15], w211 = Small[16], w212 = Small[17];
    const float w213 = Small[18], w214 = Small[19], w215 = Small[20];
    const float b2s0 = Small[21], b2s1 = Small[22];

    // ===== PHASE 1: conv for all 5 G-tiles (independent iterations) =====
    #pragma unroll
    for (int p = 0; p <= 4; ++p) {
        const int ra = 16 * p + n + (g >> 1);
        bf16x8 bk0 = *(const bf16x8*)(S + ra * 32 + (((g & 1) ^ ((ra >> 2) & 1)) << 4));
        bf16x8 bk1 = {0, 0, 0, 0, 0, 0, 0, 0};
        if (g < 2) {
            const int rb = 16 * p + n + 2;
            bk1 = *(const bf16x8*)(S + rb * 32 + ((g ^ ((rb >> 2) & 1)) << 4));
        }

        f32x4 ac0 = {cbs0, cbs0, cbs0, cbs0};
        f32x4 ac1 = {cbs1, cbs1, cbs1, cbs1};
        f32x4 ac2 = {cbs2, cbs2, cbs2, cbs2};
        ac0 = MFMA16(A1[0], bk0, ac0); ac0 = MFMA16(A1[1], bk1, ac0);
        ac1 = MFMA16(A1[2], bk0, ac1); ac1 = MFMA16(A1[3], bk1, ac1);
        ac2 = MFMA16(A1[4], bk0, ac2); ac2 = MFMA16(A1[5], bk1, ac2);

        if (p < 4 || n == 0) {
            char* gc = G + (16 * p + n) * 16 + ((g & 1) << 3) + ((g >> 1) ? GPLANE : 0);
            {
                uint2 w;
                w.x = pk2(fmaf(-2.f, rcore(ac0.x), 1.f), fmaf(-2.f, rcore(ac0.y), 1.f));
                w.y = pk2(fmaf(-2.f, rcore(ac0.z), 1.f), fmaf(-2.f, rcore(ac0.w), 1.f));
                *(uint2*)(gc + 0 * GPLANE) = w;
            }
            {
                uint2 w;
                w.x = pk2(fmaf(-2.f, rcore(ac1.x), 1.f), fmaf(-2.f, rcore(ac1.y), 1.f));
                w.y = pk2(fmaf(-2.f, rcore(ac1.z), 1.f), fmaf(-2.f, rcore(ac1.w), 1.f));
                *(uint2*)(gc + 2 * GPLANE) = w;
            }
            {
                uint2 w;
                w.x = pk2(fmaf(-2.f, rcore(ac2.x), 1.f), fmaf(-2.f, rcore(ac2.y), 1.f));
                w.y = pk2(fmaf(-2.f, rcore(ac2.z), 1.f), fmaf(-2.f, rcore(ac2.w), 1.f));
                *(uint2*)(gc + 4 * GPLANE) = w;
            }
        }
    }

    // ===== PHASE 2: FC1+FC2 for all 4 position tiles (independent iterations) =====
    #pragma unroll
    for (int p2 = 0; p2 <= 3; ++p2) {
        const int c0 = 16 * p2 + n;
        bf16x8 B0 = *(const bf16x8*)(G + g * GPLANE + c0 * 16);
        bf16x8 B1 = (g < 2)
            ? *(const bf16x8*)(G + (4 + g) * GPLANE + c0 * 16)
            : *(const bf16x8*)(G + (g - 2) * GPLANE + (c0 + 1) * 16);
        bf16x8 B2 = *(const bf16x8*)(G + (2 + g) * GPLANE + (c0 + 1) * 16);
        f32x4 h = {b1i0, b1i1, b1i2, b1i3};
        h = MFMA16(A2[0], B0, h);
        h = MFMA16(A2[1], B1, h);
        h = MFMA16(A2[2], B2, h);
        float t20 = fmaf(-2.f, rcore(h.x), 1.f);
        float t21 = fmaf(-2.f, rcore(h.y), 1.f);
        float t22 = fmaf(-2.f, rcore(h.z), 1.f);
        float t23 = fmaf(-2.f, rcore(h.w), 1.f);
        float u0 = __shfl(t20, n + 16, 64);
        float u1 = __shfl(t21, n + 16, 64);
        float y0 = b2s0 + w200 * t20 + w201 * t21 + w202 * t22 + w203 * t23
                        + w204 * u0 + w205 * u1;
        float y1 = b2s1 + w210 * t20 + w211 * t21 + w212 * t22 + w213 * t23
                        + w214 * u0 + w215 * u1;
        if (l < 16)
            reinterpret_cast<float2*>(out)[(size_t)b * TT + tb + 16 * p2 + n] =
                make_float2(y0, y1);
    }
}

extern "C" void kernel_launch(void* const* d_in, const int* in_sizes, int n_in,
                              void* d_out, int out_size, void* d_ws, size_t ws_size,
                              hipStream_t stream) {
    const float* x        = (const float*)d_in[0];
    const float* conv_w   = (const float*)d_in[1];
    const float* conv_b   = (const float*)d_in[2];
    const float* fc_hid_w = (const float*)d_in[3];
    const float* fc_hid_b = (const float*)d_in[4];
    const float* fc_out_w = (const float*)d_in[5];
    const float* fc_out_b = (const float*)d_in[6];
    float* out = (float*)d_out;

    const int grid = (BB * TT) / 256;   // 2048 blocks, ONE dispatch
    rvt_one<<<grid, 256, 0, stream>>>(x, conv_w, conv_b, fc_hid_w, fc_hid_b,
                                      fc_out_w, fc_out_b, out);
}

// Round 18
// 27.456 us; speedup vs baseline: 1.0285x; 1.0285x over previous
//
#include <hip/hip_runtime.h>

#define TT 16384
#define BB 32

typedef __attribute__((ext_vector_type(8))) short bf16x8;
typedef __attribute__((ext_vector_type(4))) float f32x4;

#define S1 2.8853900817779268f   // 2*log2(e)

__device__ __forceinline__ unsigned short f2bf(float v) {
    unsigned int u = __float_as_uint(v);
    u = (u + 0x7fffu + ((u >> 16) & 1u)) >> 16;   // RNE
    return (unsigned short)u;
}
__device__ __forceinline__ unsigned int pk2(float lo, float hi) {
    return (unsigned)f2bf(lo) | ((unsigned)f2bf(hi) << 16);
}
__device__ __forceinline__ float rcore(float v) {   // r = 1/(exp2(v)+1); tanh = 1-2r
    return __builtin_amdgcn_rcpf(__builtin_amdgcn_exp2f(v) + 1.0f);
}

// ---------------- single fused kernel, 128 positions/wave, ONE resident batch ----------------
// Grid 1024 blocks = exactly 4 blocks/CU (LDS ~25KB) -> prologue paid once.
// S: 64-row ring x 32B (slot=row&63, swizzle half = logical ^ ((row>>2)&1));
//    prologue stages rows 0..63; iter p in 1..4 stages rows 48+16p..63+16p
//    (slots consumed by tile p-1); iter 5 stages rows 128..130.
// G: 32-col ring (slot=col&31), 6 planes x 32cols x 16B; conv tile p writes
//    cols 16p..16p+15 (tile 8: col 128 only), fc tile p2=p-1 reads cols
//    16p2..16p2+16 -- all overwrites verified to land on dead slots.
__device__ __forceinline__ void stage_row(char* S, const float* __restrict__ x,
                                          int b, int tb, int i) {
    const int trow = tb - 3 + i;
    uint4 h0 = {0u, 0u, 0u, 0u}, h1 = {0u, 0u, 0u, 0u};
    if (trow >= 0 && trow < TT) {
        const float4* p = (const float4*)x + (size_t)(b * TT + trow) * 4;
        float4 f0 = p[0], f1 = p[1], f2 = p[2], f3 = p[3];
        h0.x = pk2(f0.x, f0.y); h0.y = pk2(f0.z, f0.w);
        h0.z = pk2(f1.x, f1.y); h0.w = pk2(f1.z, f1.w);
        h1.x = pk2(f2.x, f2.y); h1.y = pk2(f2.z, f2.w);
        h1.z = pk2(f3.x, f3.y); h1.w = pk2(f3.z, f3.w);
    }
    const int s = (i >> 2) & 1;
    char* base = S + (i & 63) * 32;
    *(uint4*)(base + s * 16) = h0;
    *(uint4*)(base + (s ^ 1) * 16) = h1;
}

#define MFMA16(a, bb, cc) __builtin_amdgcn_mfma_f32_16x16x32_bf16((a), (bb), (cc), 0, 0, 0)
#define GPLANE 512   // 32 cols * 16B

__global__ __launch_bounds__(256, 2) void rvt_one(
    const float* __restrict__ x,
    const float* __restrict__ conv_w, const float* __restrict__ conv_b,
    const float* __restrict__ fc_hid_w, const float* __restrict__ fc_hid_b,
    const float* __restrict__ fc_out_w, const float* __restrict__ fc_out_b,
    float* __restrict__ out)
{
    __shared__ __align__(16) char Sbuf[4 * 2048];
    __shared__ __align__(16) char Gbuf[4 * 3072];
    __shared__ __align__(16) float CwPad[576];    // [mt*4+r][48], S1-scaled, zero-padded
    __shared__ __align__(16) float FhwPad[576];   // [m<6][96], S1-scaled
    __shared__ float Small[23];

    const int tid = threadIdx.x, wv = tid >> 6, l = tid & 63;
    const int n = l & 15, g = l >> 4;
    const int m = n;
    const int P0 = blockIdx.x << 9;           // 512 positions per block
    const int b  = P0 >> 14;
    const int tb = (P0 & (TT - 1)) + (wv << 7);   // 128 positions per wave

    char* S = Sbuf + wv * 2048;
    char* G = Gbuf + wv * 3072;

    // ---- prologue: stage rows 0..63 (rows tb-3 .. tb+60) ----
    stage_row(S, x, b, tb, l);

    // ---- build pre-scaled weight tables (block-cooperative, coalesced) ----
    for (int i = tid; i < 576; i += 256) FhwPad[i] = S1 * fc_hid_w[i];
    for (int s = tid; s < 576; s += 256) {
        const int r = (s / 48) & 3, kcp = s % 48;
        if (!(r < 3 && kcp >= 14 && kcp <= 16)) CwPad[s] = 0.f;
    }
    if (tid < 27) {
        const int mt = tid / 9, r = (tid % 9) / 3, kc = tid % 3;
        CwPad[(mt * 4 + r) * 48 + 14 + kc] = S1 * conv_w[tid];
    } else if (tid < 30) Small[tid - 27] = S1 * conv_b[tid - 27];
    else if (tid < 36) Small[3 + tid - 30] = S1 * fc_hid_b[tid - 30];
    else if (tid < 48) Small[9 + tid - 36] = fc_out_w[tid - 36];
    else if (tid < 50) Small[21 + tid - 48] = fc_out_b[tid - 48];
    __syncthreads();

    // ---- per-lane A-fragment gather from LDS ----
    union { uint4 u; bf16x8 f; } cv;
    bf16x8 A1[6], A2[3];
    #pragma unroll
    for (int mt = 0; mt < 3; ++mt)
        #pragma unroll
        for (int kt = 0; kt < 2; ++kt) {
            const int rr = kt * 2 + (g >> 1);
            const float* p = &CwPad[(mt * 4 + rr) * 48 + ((g & 1) * 8 - m + 15)];
            cv.u.x = pk2(p[0], p[1]);
            cv.u.y = pk2(p[2], p[3]);
            cv.u.z = pk2(p[4], p[5]);
            cv.u.w = pk2(p[6], p[7]);
            A1[mt * 2 + kt] = cv.f;
        }
    {
        const unsigned umask = (m < 6) ? 0xFFFFFFFFu : 0u;
        const int mc = (m < 6) ? m : 5;
        #pragma unroll
        for (int kt2 = 0; kt2 < 3; ++kt2) {
            const int q0 = kt2 * 32 + g * 8;
            const int wr = (q0 >= 48) ? 1 : 0;
            const int col0 = q0 - 48 * wr;
            const int oc = col0 >> 4, c0 = col0 & 15;
            const float4* fp = (const float4*)&FhwPad[mc * 96 + (oc * 2 + wr) * 16 + c0];
            float4 a = fp[0], bq = fp[1];
            cv.u.x = pk2(a.x, a.y) & umask;
            cv.u.y = pk2(a.z, a.w) & umask;
            cv.u.z = pk2(bq.x, bq.y) & umask;
            cv.u.w = pk2(bq.z, bq.w) & umask;
            A2[kt2] = cv.f;
        }
    }

    const float cbs0 = Small[0], cbs1 = Small[1], cbs2 = Small[2];
    const int r0 = g * 4;
    const float b1i0 = (r0 + 0 < 6) ? Small[3 + r0 + 0] : 0.f;
    const float b1i1 = (r0 + 1 < 6) ? Small[3 + r0 + 1] : 0.f;
    const float b1i2 = (r0 + 2 < 6) ? Small[3 + r0 + 2] : 0.f;
    const float b1i3 = (r0 + 3 < 6) ? Small[3 + r0 + 3] : 0.f;
    const float w200 = Small[9],  w201 = Small[10], w202 = Small[11];
    const float w203 = Small[12], w204 = Small[13], w205 = Small[14];
    const float w210 = Small[15], w211 = Small[16], w212 = Small[17];
    const float w213 = Small[18], w214 = Small[19], w215 = Small[20];
    const float b2s0 = Small[21], b2s1 = Small[22];

    #pragma unroll
    for (int p = 0; p <= 8; ++p) {
        // ---- incremental staging: rows for tile p+1.. (slots freed by tile p-1) ----
        if (p >= 1 && p <= 4) {
            if (l < 16) stage_row(S, x, b, tb, 48 + 16 * p + l);   // rows 64..127
        } else if (p == 5) {
            if (l < 3) stage_row(S, x, b, tb, 128 + l);            // rows 128..130
        }

        // ===== MFMA1: conv for G-columns 16p..16p+15 (p=8: col 128 only) =====
        const int ra = 16 * p + n + (g >> 1);
        bf16x8 bk0 = *(const bf16x8*)(S + (ra & 63) * 32 + (((g & 1) ^ ((ra >> 2) & 1)) << 4));
        bf16x8 bk1 = {0, 0, 0, 0, 0, 0, 0, 0};
        if (g < 2) {
            const int rb = 16 * p + n + 2;
            bk1 = *(const bf16x8*)(S + (rb & 63) * 32 + ((g ^ ((rb >> 2) & 1)) << 4));
        }

        f32x4 ac0 = {cbs0, cbs0, cbs0, cbs0};
        f32x4 ac1 = {cbs1, cbs1, cbs1, cbs1};
        f32x4 ac2 = {cbs2, cbs2, cbs2, cbs2};
        ac0 = MFMA16(A1[0], bk0, ac0); ac0 = MFMA16(A1[1], bk1, ac0);
        ac1 = MFMA16(A1[2], bk0, ac1); ac1 = MFMA16(A1[3], bk1, ac1);
        ac2 = MFMA16(A1[4], bk0, ac2); ac2 = MFMA16(A1[5], bk1, ac2);

        if (p < 8 || n == 0) {
            char* gc = G + ((16 * p + n) & 31) * 16 + ((g & 1) << 3) + ((g >> 1) ? GPLANE : 0);
            {
                uint2 w;
                w.x = pk2(fmaf(-2.f, rcore(ac0.x), 1.f), fmaf(-2.f, rcore(ac0.y), 1.f));
                w.y = pk2(fmaf(-2.f, rcore(ac0.z), 1.f), fmaf(-2.f, rcore(ac0.w), 1.f));
                *(uint2*)(gc + 0 * GPLANE) = w;
            }
            {
                uint2 w;
                w.x = pk2(fmaf(-2.f, rcore(ac1.x), 1.f), fmaf(-2.f, rcore(ac1.y), 1.f));
                w.y = pk2(fmaf(-2.f, rcore(ac1.z), 1.f), fmaf(-2.f, rcore(ac1.w), 1.f));
                *(uint2*)(gc + 2 * GPLANE) = w;
            }
            {
                uint2 w;
                w.x = pk2(fmaf(-2.f, rcore(ac2.x), 1.f), fmaf(-2.f, rcore(ac2.y), 1.f));
                w.y = pk2(fmaf(-2.f, rcore(ac2.z), 1.f), fmaf(-2.f, rcore(ac2.w), 1.f));
                *(uint2*)(gc + 4 * GPLANE) = w;
            }
        }

        // ===== MFMA2: FC1+FC2 for position tile p2=p-1 =====
        if (p >= 1) {
            const int p2 = p - 1;
            const int c0 = 16 * p2 + n;
            bf16x8 B0 = *(const bf16x8*)(G + g * GPLANE + (c0 & 31) * 16);
            bf16x8 B1 = (g < 2)
                ? *(const bf16x8*)(G + (4 + g) * GPLANE + (c0 & 31) * 16)
                : *(const bf16x8*)(G + (g - 2) * GPLANE + ((c0 + 1) & 31) * 16);
            bf16x8 B2 = *(const bf16x8*)(G + (2 + g) * GPLANE + ((c0 + 1) & 31) * 16);
            f32x4 h = {b1i0, b1i1, b1i2, b1i3};
            h = MFMA16(A2[0], B0, h);
            h = MFMA16(A2[1], B1, h);
            h = MFMA16(A2[2], B2, h);
            float t20 = fmaf(-2.f, rcore(h.x), 1.f);
            float t21 = fmaf(-2.f, rcore(h.y), 1.f);
            float t22 = fmaf(-2.f, rcore(h.z), 1.f);
            float t23 = fmaf(-2.f, rcore(h.w), 1.f);
            float u0 = __shfl(t20, n + 16, 64);
            float u1 = __shfl(t21, n + 16, 64);
            float y0 = b2s0 + w200 * t20 + w201 * t21 + w202 * t22 + w203 * t23
                            + w204 * u0 + w205 * u1;
            float y1 = b2s1 + w210 * t20 + w211 * t21 + w212 * t22 + w213 * t23
                            + w214 * u0 + w215 * u1;
            if (l < 16)
                reinterpret_cast<float2*>(out)[(size_t)b * TT + tb + 16 * p2 + n] =
                    make_float2(y0, y1);
        }
    }
}

extern "C" void kernel_launch(void* const* d_in, const int* in_sizes, int n_in,
                              void* d_out, int out_size, void* d_ws, size_t ws_size,
                              hipStream_t stream) {
    const float* x        = (const float*)d_in[0];
    const float* conv_w   = (const float*)d_in[1];
    const float* conv_b   = (const float*)d_in[2];
    const float* fc_hid_w = (const float*)d_in[3];
    const float* fc_hid_b = (const float*)d_in[4];
    const float* fc_out_w = (const float*)d_in[5];
    const float* fc_out_b = (const float*)d_in[6];
    float* out = (float*)d_out;

    const int grid = (BB * TT) / 512;   // 1024 blocks = 4 blocks/CU, ONE batch
    rvt_one<<<grid, 256, 0, stream>>>(x, conv_w, conv_b, fc_hid_w, fc_hid_b,
                                      fc_out_w, fc_out_b, out);
}

// Round 19
// 24.527 us; speedup vs baseline: 1.1514x; 1.1194x over previous
//
#include <hip/hip_runtime.h>

#define TT 16384
#define BB 32

typedef __attribute__((ext_vector_type(8))) short bf16x8;
typedef __attribute__((ext_vector_type(4))) float f32x4;

#define S1 2.8853900817779268f   // 2*log2(e)

__device__ __forceinline__ unsigned short f2bf(float v) {   // RNE, weights/one-time only
    unsigned int u = __float_as_uint(v);
    u = (u + 0x7fffu + ((u >> 16) & 1u)) >> 16;
    return (unsigned short)u;
}
__device__ __forceinline__ unsigned int pk2(float lo, float hi) {   // RNE pack (cold paths)
    return (unsigned)f2bf(lo) | ((unsigned)f2bf(hi) << 16);
}
// HOT pack: truncating, 1 VALU (v_perm_b32). bf16 trunc costs <=1 ulp extra.
__device__ __forceinline__ unsigned int pk2t(float lo, float hi) {
#if __has_builtin(__builtin_amdgcn_perm)
    return __builtin_amdgcn_perm(__float_as_uint(hi), __float_as_uint(lo), 0x07060302u);
#else
    return (__float_as_uint(hi) & 0xFFFF0000u) | (__float_as_uint(lo) >> 16);
#endif
}
__device__ __forceinline__ float rcore(float v) {   // r = 1/(exp2(v)+1); tanh = 1-2r
    return __builtin_amdgcn_rcpf(__builtin_amdgcn_exp2f(v) + 1.0f);
}

// ---------------- single fused kernel (round-18 structure, verified 27.46us) ----------------
// Change this round: stage_row and G-pack use pk2t (1-op truncating pack) instead
// of the 12-op RNE pk2. Weight paths (CwPad/FhwPad gathers) keep RNE.
__device__ __forceinline__ void stage_row(char* S, const float* __restrict__ x,
                                          int b, int tb, int i) {
    const int trow = tb - 3 + i;
    uint4 h0 = {0u, 0u, 0u, 0u}, h1 = {0u, 0u, 0u, 0u};
    if (trow >= 0 && trow < TT) {
        const float4* p = (const float4*)x + (size_t)(b * TT + trow) * 4;
        float4 f0 = p[0], f1 = p[1], f2 = p[2], f3 = p[3];
        h0.x = pk2t(f0.x, f0.y); h0.y = pk2t(f0.z, f0.w);
        h0.z = pk2t(f1.x, f1.y); h0.w = pk2t(f1.z, f1.w);
        h1.x = pk2t(f2.x, f2.y); h1.y = pk2t(f2.z, f2.w);
        h1.z = pk2t(f3.x, f3.y); h1.w = pk2t(f3.z, f3.w);
    }
    const int s = (i >> 2) & 1;
    char* base = S + (i & 63) * 32;
    *(uint4*)(base + s * 16) = h0;
    *(uint4*)(base + (s ^ 1) * 16) = h1;
}

#define MFMA16(a, bb, cc) __builtin_amdgcn_mfma_f32_16x16x32_bf16((a), (bb), (cc), 0, 0, 0)
#define GPLANE 512   // 32 cols * 16B

__global__ __launch_bounds__(256, 2) void rvt_one(
    const float* __restrict__ x,
    const float* __restrict__ conv_w, const float* __restrict__ conv_b,
    const float* __restrict__ fc_hid_w, const float* __restrict__ fc_hid_b,
    const float* __restrict__ fc_out_w, const float* __restrict__ fc_out_b,
    float* __restrict__ out)
{
    __shared__ __align__(16) char Sbuf[4 * 2048];
    __shared__ __align__(16) char Gbuf[4 * 3072];
    __shared__ __align__(16) float CwPad[576];
    __shared__ __align__(16) float FhwPad[576];
    __shared__ float Small[23];

    const int tid = threadIdx.x, wv = tid >> 6, l = tid & 63;
    const int n = l & 15, g = l >> 4;
    const int m = n;
    const int P0 = blockIdx.x << 9;               // 512 positions per block
    const int b  = P0 >> 14;
    const int tb = (P0 & (TT - 1)) + (wv << 7);   // 128 positions per wave

    char* S = Sbuf + wv * 2048;
    char* G = Gbuf + wv * 3072;

    // ---- prologue: stage rows 0..63 (rows tb-3 .. tb+60) ----
    stage_row(S, x, b, tb, l);

    // ---- build pre-scaled weight tables ----
    for (int i = tid; i < 576; i += 256) FhwPad[i] = S1 * fc_hid_w[i];
    for (int s = tid; s < 576; s += 256) {
        const int r = (s / 48) & 3, kcp = s % 48;
        if (!(r < 3 && kcp >= 14 && kcp <= 16)) CwPad[s] = 0.f;
    }
    if (tid < 27) {
        const int mt = tid / 9, r = (tid % 9) / 3, kc = tid % 3;
        CwPad[(mt * 4 + r) * 48 + 14 + kc] = S1 * conv_w[tid];
    } else if (tid < 30) Small[tid - 27] = S1 * conv_b[tid - 27];
    else if (tid < 36) Small[3 + tid - 30] = S1 * fc_hid_b[tid - 30];
    else if (tid < 48) Small[9 + tid - 36] = fc_out_w[tid - 36];
    else if (tid < 50) Small[21 + tid - 48] = fc_out_b[tid - 48];
    __syncthreads();

    // ---- per-lane A-fragment gather from LDS (RNE: weights, one-time) ----
    union { uint4 u; bf16x8 f; } cv;
    bf16x8 A1[6], A2[3];
    #pragma unroll
    for (int mt = 0; mt < 3; ++mt)
        #pragma unroll
        for (int kt = 0; kt < 2; ++kt) {
            const int rr = kt * 2 + (g >> 1);
            const float* p = &CwPad[(mt * 4 + rr) * 48 + ((g & 1) * 8 - m + 15)];
            cv.u.x = pk2(p[0], p[1]);
            cv.u.y = pk2(p[2], p[3]);
            cv.u.z = pk2(p[4], p[5]);
            cv.u.w = pk2(p[6], p[7]);
            A1[mt * 2 + kt] = cv.f;
        }
    {
        const unsigned umask = (m < 6) ? 0xFFFFFFFFu : 0u;
        const int mc = (m < 6) ? m : 5;
        #pragma unroll
        for (int kt2 = 0; kt2 < 3; ++kt2) {
            const int q0 = kt2 * 32 + g * 8;
            const int wr = (q0 >= 48) ? 1 : 0;
            const int col0 = q0 - 48 * wr;
            const int oc = col0 >> 4, c0 = col0 & 15;
            const float4* fp = (const float4*)&FhwPad[mc * 96 + (oc * 2 + wr) * 16 + c0];
            float4 a = fp[0], bq = fp[1];
            cv.u.x = pk2(a.x, a.y) & umask;
            cv.u.y = pk2(a.z, a.w) & umask;
            cv.u.z = pk2(bq.x, bq.y) & umask;
            cv.u.w = pk2(bq.z, bq.w) & umask;
            A2[kt2] = cv.f;
        }
    }

    const float cbs0 = Small[0], cbs1 = Small[1], cbs2 = Small[2];
    const int r0 = g * 4;
    const float b1i0 = (r0 + 0 < 6) ? Small[3 + r0 + 0] : 0.f;
    const float b1i1 = (r0 + 1 < 6) ? Small[3 + r0 + 1] : 0.f;
    const float b1i2 = (r0 + 2 < 6) ? Small[3 + r0 + 2] : 0.f;
    const float b1i3 = (r0 + 3 < 6) ? Small[3 + r0 + 3] : 0.f;
    const float w200 = Small[9],  w201 = Small[10], w202 = Small[11];
    const float w203 = Small[12], w204 = Small[13], w205 = Small[14];
    const float w210 = Small[15], w211 = Small[16], w212 = Small[17];
    const float w213 = Small[18], w214 = Small[19], w215 = Small[20];
    const float b2s0 = Small[21], b2s1 = Small[22];

    #pragma unroll
    for (int p = 0; p <= 8; ++p) {
        // ---- incremental staging (slots freed by tile p-1) ----
        if (p >= 1 && p <= 4) {
            if (l < 16) stage_row(S, x, b, tb, 48 + 16 * p + l);   // rows 64..127
        } else if (p == 5) {
            if (l < 3) stage_row(S, x, b, tb, 128 + l);            // rows 128..130
        }

        // ===== MFMA1: conv for G-columns 16p..16p+15 (p=8: col 128 only) =====
        const int ra = 16 * p + n + (g >> 1);
        bf16x8 bk0 = *(const bf16x8*)(S + (ra & 63) * 32 + (((g & 1) ^ ((ra >> 2) & 1)) << 4));
        bf16x8 bk1 = {0, 0, 0, 0, 0, 0, 0, 0};
        if (g < 2) {
            const int rb = 16 * p + n + 2;
            bk1 = *(const bf16x8*)(S + (rb & 63) * 32 + ((g ^ ((rb >> 2) & 1)) << 4));
        }

        f32x4 ac0 = {cbs0, cbs0, cbs0, cbs0};
        f32x4 ac1 = {cbs1, cbs1, cbs1, cbs1};
        f32x4 ac2 = {cbs2, cbs2, cbs2, cbs2};
        ac0 = MFMA16(A1[0], bk0, ac0); ac0 = MFMA16(A1[1], bk1, ac0);
        ac1 = MFMA16(A1[2], bk0, ac1); ac1 = MFMA16(A1[3], bk1, ac1);
        ac2 = MFMA16(A1[4], bk0, ac2); ac2 = MFMA16(A1[5], bk1, ac2);

        if (p < 8 || n == 0) {
            char* gc = G + ((16 * p + n) & 31) * 16 + ((g & 1) << 3) + ((g >> 1) ? GPLANE : 0);
            {
                uint2 w;
                w.x = pk2t(fmaf(-2.f, rcore(ac0.x), 1.f), fmaf(-2.f, rcore(ac0.y), 1.f));
                w.y = pk2t(fmaf(-2.f, rcore(ac0.z), 1.f), fmaf(-2.f, rcore(ac0.w), 1.f));
                *(uint2*)(gc + 0 * GPLANE) = w;
            }
            {
                uint2 w;
                w.x = pk2t(fmaf(-2.f, rcore(ac1.x), 1.f), fmaf(-2.f, rcore(ac1.y), 1.f));
                w.y = pk2t(fmaf(-2.f, rcore(ac1.z), 1.f), fmaf(-2.f, rcore(ac1.w), 1.f));
                *(uint2*)(gc + 2 * GPLANE) = w;
            }
            {
                uint2 w;
                w.x = pk2t(fmaf(-2.f, rcore(ac2.x), 1.f), fmaf(-2.f, rcore(ac2.y), 1.f));
                w.y = pk2t(fmaf(-2.f, rcore(ac2.z), 1.f), fmaf(-2.f, rcore(ac2.w), 1.f));
                *(uint2*)(gc + 4 * GPLANE) = w;
            }
        }

        // ===== MFMA2: FC1+FC2 for position tile p2=p-1 =====
        if (p >= 1) {
            const int p2 = p - 1;
            const int c0 = 16 * p2 + n;
            bf16x8 B0 = *(const bf16x8*)(G + g * GPLANE + (c0 & 31) * 16);
            bf16x8 B1 = (g < 2)
                ? *(const bf16x8*)(G + (4 + g) * GPLANE + (c0 & 31) * 16)
                : *(const bf16x8*)(G + (g - 2) * GPLANE + ((c0 + 1) & 31) * 16);
            bf16x8 B2 = *(const bf16x8*)(G + (2 + g) * GPLANE + ((c0 + 1) & 31) * 16);
            f32x4 h = {b1i0, b1i1, b1i2, b1i3};
            h = MFMA16(A2[0], B0, h);
            h = MFMA16(A2[1], B1, h);
            h = MFMA16(A2[2], B2, h);
            float t20 = fmaf(-2.f, rcore(h.x), 1.f);
            float t21 = fmaf(-2.f, rcore(h.y), 1.f);
            float t22 = fmaf(-2.f, rcore(h.z), 1.f);
            float t23 = fmaf(-2.f, rcore(h.w), 1.f);
            float u0 = __shfl(t20, n + 16, 64);
            float u1 = __shfl(t21, n + 16, 64);
            float y0 = b2s0 + w200 * t20 + w201 * t21 + w202 * t22 + w203 * t23
                            + w204 * u0 + w205 * u1;
            float y1 = b2s1 + w210 * t20 + w211 * t21 + w212 * t22 + w213 * t23
                            + w214 * u0 + w215 * u1;
            if (l < 16)
                reinterpret_cast<float2*>(out)[(size_t)b * TT + tb + 16 * p2 + n] =
                    make_float2(y0, y1);
        }
    }
}

extern "C" void kernel_launch(void* const* d_in, const int* in_sizes, int n_in,
                              void* d_out, int out_size, void* d_ws, size_t ws_size,
                              hipStream_t stream) {
    const float* x        = (const float*)d_in[0];
    const float* conv_w   = (const float*)d_in[1];
    const float* conv_b   = (const float*)d_in[2];
    const float* fc_hid_w = (const float*)d_in[3];
    const float* fc_hid_b = (const float*)d_in[4];
    const float* fc_out_w = (const float*)d_in[5];
    const float* fc_out_b = (const float*)d_in[6];
    float* out = (float*)d_out;

    const int grid = (BB * TT) / 512;   // 1024 blocks = 4 blocks/CU, ONE batch
    rvt_one<<<grid, 256, 0, stream>>>(x, conv_w, conv_b, fc_hid_w, fc_hid_b,
                                      fc_out_w, fc_out_b, out);
}